// Round 7
// baseline (514.161 us; speedup 1.0000x reference)
//
#include <hip/hip_runtime.h>
#include <hip/hip_bf16.h>
#include <math.h>

#define B_ 16
#define S_ 4096
#define E_ 1024
#define H_ 512

#define BM 128
#define BN 128
#define BK 64
#define NCHUNK (E_ / BK)  // 16

typedef short bf16x8 __attribute__((ext_vector_type(8)));
typedef unsigned short u16x8 __attribute__((ext_vector_type(8)));
typedef float f32x4 __attribute__((ext_vector_type(4)));

__device__ inline unsigned short f2bf(float x) {
    __hip_bfloat16 h = __float2bfloat16(x);
    return *(unsigned short*)&h;
}
__device__ inline float bf2f(unsigned short u) {
    unsigned int x = ((unsigned int)u) << 16;
    float f;
    __builtin_memcpy(&f, &x, 4);
    return f;
}
__device__ __forceinline__ void gld16(const unsigned short* g, unsigned short* l) {
    __builtin_amdgcn_global_load_lds(
        (const __attribute__((address_space(1))) void*)g,
        (__attribute__((address_space(3))) void*)l, 16, 0, 0);
}

// Prep (tiny now):
//  blocks 0..63   : We -> WeTcB bf16, swizzled-chunk layout:
//                   WeTcB[c*32768 + n*64 + cp*8 + j] = We[k][n],
//                   k = c*64 + (cp ^ (n&7))*8 + j   (bank-conflict-free frags)
//  blocks 64..191 : dp[b][h] = dec[b,:].Wd[:,h] + bd[h] + be[h] (bo: softmax-inv)
__global__ __launch_bounds__(256) void prep_kernel(
    const float* __restrict__ We, const float* __restrict__ dec,
    const float* __restrict__ Wd, const float* __restrict__ bd,
    const float* __restrict__ be, unsigned short* __restrict__ WeTcB,
    float* __restrict__ dp) {
    __shared__ float red[4][64];
    int bid = blockIdx.x, t = threadIdx.x;
    if (bid < 64) {
        int c = bid >> 2, n0t = (bid & 3) * 128;
#pragma unroll 4
        for (int it = 0; it < 32; ++it) {
            int o = it * 256 + t;
            int n_rel = o >> 6, within = o & 63;
            int cp = within >> 3, j = within & 7;
            int n = n0t + n_rel;
            int k = c * 64 + ((cp ^ (n & 7)) << 3) + j;
            WeTcB[c * 32768 + n * 64 + within] = f2bf(We[(size_t)k * H_ + n]);
        }
    } else {
        int id = bid - 64;
        int b = id >> 3, hc = id & 7;
        int h = hc * 64 + (t & 63);
        int ec = t >> 6;
        const float* dr = dec + b * E_ + ec * 256;
        const float* wp = Wd + (size_t)(ec * 256) * H_ + h;
        float acc = 0.f;
#pragma unroll 8
        for (int e = 0; e < 256; ++e) acc = fmaf(dr[e], wp[(size_t)e * H_], acc);
        red[ec][t & 63] = acc;
        __syncthreads();
        if (t < 64) {
            int hh = hc * 64 + t;
            dp[b * H_ + hh] = red[0][t] + red[1][t] + red[2][t] + red[3][t] + bd[hh] + be[hh];
        }
    }
}

// Fused GEMM: parts[nt][b][s] = sum_{h in nt's 128} tanh(enc@We + dp)*Wo
// 128x128x64 tiles, 4 waves (2m x 2n), acc 4x4 frags = 64 AGPR/lane.
// A: fp32 enc loaded to regs, converted bf16, ds_write_b128 with XOR swizzle
//    (phys k-block = logical ^ (row&7)) -> conflict-free ds_read_b128 frags.
//    nt==0 siblings also emit the linear bf16 encB copy for the ctx pass.
// B: pre-swizzled WeTcB staged via global_load_lds(16B), async.
// Block remap: 4 nt-siblings of an m-tile land on the same XCD (bid%8 heuristic)
// so the fp32 A-tile is fetched once into that XCD's L2.
__global__ __launch_bounds__(256, 3) void scores_gemm_kernel(
    const float* __restrict__ enc, const unsigned short* __restrict__ WeTcB,
    const float* __restrict__ Wo, const float* __restrict__ dp,
    float* __restrict__ parts, unsigned short* __restrict__ encB) {
    __shared__ unsigned short sA[BM * BK];  // 16 KB
    __shared__ unsigned short sB[BN * BK];  // 16 KB
    __shared__ float sRed[2][BM];

    int tid = threadIdx.x;
    int w = tid >> 6, l = tid & 63;
    int l16 = l & 15, quad = l >> 4;
    int wm = w & 1, wn = w >> 1;
    int bid = blockIdx.x;
    int xcd = bid & 7;
    int sq = bid >> 3;
    int nt = sq & 3;                             // sibling index (same XCD for all 4)
    size_t mt = (size_t)((sq >> 2) << 3) + xcd;  // [0,512)
    size_t m0 = mt * BM;
    int n0 = nt * BN;
    int b = (int)(m0 >> 12);
    bool writeB = (nt == 0);

    // A staging lane constants: row = tid>>3 (+32*it), k-block = tid&7
    int arowS = tid >> 3;
    int akb = tid & 7;
    const float* gAf = enc + (m0 + arowS) * E_ + akb * 8;
    unsigned short* sAw = sA + arowS * BK + ((akb ^ (arowS & 7)) << 3);
    unsigned short* encBw = encB + (m0 + arowS) * E_ + akb * 8;
    // B staging lane constants (gld16: wave-uniform base + lane*16B)
    const unsigned short* gB = WeTcB + (size_t)n0 * BK + (w * 8) * BK + l * 8;
    unsigned short* sBb = sB + (w * 8) * BK;

    f32x4 acc[4][4];
#pragma unroll
    for (int i = 0; i < 4; ++i)
#pragma unroll
        for (int j = 0; j < 4; ++j) acc[i][j] = (f32x4)0.f;

    int arow = (wm * 64 + l16) * BK;
    int brow = (wn * 64 + l16) * BK;
    int sw = l16 & 7;

    for (int c = 0; c < NCHUNK; ++c) {
        __syncthreads();  // prior chunk's frag reads complete
        int k0 = c * BK;
        // B: async direct-to-LDS
#pragma unroll
        for (int i = 0; i < 4; ++i)
            gld16(gB + (size_t)c * (H_ * BK) + i * 32 * BK, sBb + i * 32 * BK);
        // A: fp32 -> bf16 -> LDS (+ encB for ctx, nt==0 only)
#pragma unroll
        for (int it = 0; it < 4; ++it) {
            const float* p = gAf + (size_t)it * 32 * E_ + k0;
            float4 va = *(const float4*)(p);
            float4 vb = *(const float4*)(p + 4);
            u16x8 u;
            u[0] = f2bf(va.x); u[1] = f2bf(va.y); u[2] = f2bf(va.z); u[3] = f2bf(va.w);
            u[4] = f2bf(vb.x); u[5] = f2bf(vb.y); u[6] = f2bf(vb.z); u[7] = f2bf(vb.w);
            *(u16x8*)(sAw + it * 32 * BK) = u;
            if (writeB) *(u16x8*)(encBw + (size_t)it * 32 * E_ + k0) = u;
        }
        __syncthreads();  // staging visible (compiler drains vm/lgkm before barrier)
#pragma unroll
        for (int half = 0; half < 2; ++half) {
            int koff = (((half * 4 + quad) ^ sw) << 3);
            bf16x8 aR[4], bR[4];
#pragma unroll
            for (int i = 0; i < 4; ++i)
                aR[i] = *(const bf16x8*)(sA + arow + i * 16 * BK + koff);
#pragma unroll
            for (int j = 0; j < 4; ++j)
                bR[j] = *(const bf16x8*)(sB + brow + j * 16 * BK + koff);
#pragma unroll
            for (int i = 0; i < 4; ++i)
#pragma unroll
                for (int j = 0; j < 4; ++j)
                    acc[i][j] = __builtin_amdgcn_mfma_f32_16x16x32_bf16(aR[i], bR[j], acc[i][j], 0, 0, 0);
        }
    }

    // Epilogue: tanh(acc + dp) * Wo, partial reduce over this block's 128 h.
    float dpv[4], wov[4];
    const float* dpb = dp + b * H_;
#pragma unroll
    for (int j = 0; j < 4; ++j) {
        int h = n0 + wn * 64 + j * 16 + l16;
        dpv[j] = dpb[h];
        wov[j] = Wo[h];
    }
#pragma unroll
    for (int i = 0; i < 4; ++i)
#pragma unroll
        for (int r = 0; r < 4; ++r) {
            float s = 0.f;
#pragma unroll
            for (int j = 0; j < 4; ++j) {
                float x = acc[i][j][r] + dpv[j];
                float e = __expf(2.f * x);
                s += (1.f - 2.f / (e + 1.f)) * wov[j];
            }
            s += __shfl_xor(s, 1, 64);
            s += __shfl_xor(s, 2, 64);
            s += __shfl_xor(s, 4, 64);
            s += __shfl_xor(s, 8, 64);
            if (l16 == 0) sRed[wn][wm * 64 + i * 16 + quad * 4 + r] = s;
        }
    __syncthreads();
    if (tid < BM) {
        int s_in = (int)(m0 & (S_ - 1)) + tid;
        parts[(size_t)(nt * B_ + b) * S_ + s_in] = sRed[0][tid] + sRed[1][tid];
    }
}

// Row softmax stats only: stats[b] = (max, sumexp) over summed 4-slab scores.
__global__ __launch_bounds__(256) void stats_kernel(const float* __restrict__ parts,
                                                    float2* __restrict__ stats) {
    int b = blockIdx.x, tid = threadIdx.x;
    const float4* p0 = (const float4*)(parts + (size_t)(0 * B_ + b) * S_);
    const float4* p1 = (const float4*)(parts + (size_t)(1 * B_ + b) * S_);
    const float4* p2 = (const float4*)(parts + (size_t)(2 * B_ + b) * S_);
    const float4* p3 = (const float4*)(parts + (size_t)(3 * B_ + b) * S_);
    float4 v[4];
    float m = -1e30f;
#pragma unroll
    for (int i = 0; i < 4; ++i) {
        int idx = i * 256 + tid;
        float4 a0 = p0[idx], a1 = p1[idx], a2 = p2[idx], a3 = p3[idx];
        v[i].x = a0.x + a1.x + a2.x + a3.x;
        v[i].y = a0.y + a1.y + a2.y + a3.y;
        v[i].z = a0.z + a1.z + a2.z + a3.z;
        v[i].w = a0.w + a1.w + a2.w + a3.w;
        m = fmaxf(m, fmaxf(fmaxf(v[i].x, v[i].y), fmaxf(v[i].z, v[i].w)));
    }
    for (int off = 32; off; off >>= 1) m = fmaxf(m, __shfl_xor(m, off, 64));
    __shared__ float redm[4];
    __shared__ float reds[4];
    if ((tid & 63) == 0) redm[tid >> 6] = m;
    __syncthreads();
    m = fmaxf(fmaxf(redm[0], redm[1]), fmaxf(redm[2], redm[3]));
    float s = 0.f;
#pragma unroll
    for (int i = 0; i < 4; ++i) {
        s += __expf(v[i].x - m) + __expf(v[i].y - m);
        s += __expf(v[i].z - m) + __expf(v[i].w - m);
    }
    for (int off = 32; off; off >>= 1) s += __shfl_xor(s, off, 64);
    if ((tid & 63) == 0) reds[tid >> 6] = s;
    __syncthreads();
    if (tid == 0) {
        stats[b] = make_float2(m, reds[0] + reds[1] + reds[2] + reds[3]);
    }
}

// ctx partials from bf16 enc copy, unnormalized weights exp(sc - m).
__global__ __launch_bounds__(256) void ctx_partial_bf16(
    const unsigned short* __restrict__ encB, const float* __restrict__ parts,
    const float2* __restrict__ stats, float* __restrict__ part) {
    int b = blockIdx.x >> 5;
    int c = blockIdx.x & 31;
    int s0 = c * 128;
    int tid = threadIdx.x;
    __shared__ float w[128];
    if (tid < 128) {
        size_t idx = (size_t)b * S_ + s0 + tid;
        float x = parts[(size_t)(0 * B_) * S_ + idx] + parts[(size_t)(1 * B_) * S_ + idx] +
                  parts[(size_t)(2 * B_) * S_ + idx] + parts[(size_t)(3 * B_) * S_ + idx];
        w[tid] = __expf(x - stats[b].x);
    }
    __syncthreads();
    int e8 = (tid & 127) * 8;
    int sh = tid >> 7;
    const unsigned short* base = encB + ((size_t)b * S_ + s0 + sh * 64) * E_ + e8;
    const float* wp = w + sh * 64;
    float acc[8];
#pragma unroll
    for (int t = 0; t < 8; ++t) acc[t] = 0.f;
    for (int s = 0; s < 64; s += 8) {
        u16x8 v[8];
#pragma unroll
        for (int u = 0; u < 8; ++u) v[u] = *(const u16x8*)(base + (size_t)(s + u) * E_);
#pragma unroll
        for (int u = 0; u < 8; ++u) {
            float ws = wp[s + u];
#pragma unroll
            for (int t = 0; t < 8; ++t) acc[t] = fmaf(ws, bf2f(v[u][t]), acc[t]);
        }
    }
    float* po = part + ((size_t)(b * 64 + c * 2 + sh)) * E_ + e8;
    *(float4*)(po) = make_float4(acc[0], acc[1], acc[2], acc[3]);
    *(float4*)(po + 4) = make_float4(acc[4], acc[5], acc[6], acc[7]);
}

__global__ __launch_bounds__(256) void ctx_reduce(const float* __restrict__ part,
                                                  const float2* __restrict__ stats,
                                                  float* __restrict__ out) {
    int idx = blockIdx.x * 256 + threadIdx.x;  // 16*1024
    int b = idx >> 10;
    int e = idx & 1023;
    const float* p = part + (size_t)b * 64 * E_ + e;
    float s0 = 0.f, s1 = 0.f, s2 = 0.f, s3 = 0.f;
    for (int c = 0; c < 64; c += 4) {
        s0 += p[(size_t)(c + 0) * E_];
        s1 += p[(size_t)(c + 1) * E_];
        s2 += p[(size_t)(c + 2) * E_];
        s3 += p[(size_t)(c + 3) * E_];
    }
    out[idx] = ((s0 + s1) + (s2 + s3)) * (1.f / stats[b].y);
}

extern "C" void kernel_launch(void* const* d_in, const int* in_sizes, int n_in,
                              void* d_out, int out_size, void* d_ws, size_t ws_size,
                              hipStream_t stream) {
    const float* enc = (const float*)d_in[0];  // [16,4096,1024]
    const float* dec = (const float*)d_in[1];  // [16,1024]
    const float* We  = (const float*)d_in[2];  // [1024,512]
    const float* be  = (const float*)d_in[3];  // [512]
    const float* Wd  = (const float*)d_in[4];  // [1024,512]
    const float* bd  = (const float*)d_in[5];  // [512]
    const float* Wo  = (const float*)d_in[6];  // [512,1]
    float* out = (float*)d_out;                // [16,1024]

    char* wsp = (char*)d_ws;
    unsigned short* WeTcB = (unsigned short*)wsp;              // 1 MiB
    float* dp = (float*)(wsp + (1 << 20));                     // 32 KiB
    float2* stats = (float2*)(wsp + (1 << 20) + (32 << 10));   // 128 B
    float* parts = (float*)(wsp + (1 << 20) + (64 << 10));     // 1 MiB (4 slabs)
    float* part = (float*)(wsp + (4 << 20));                   // 4 MiB
    unsigned short* encB = (unsigned short*)(wsp + (8 << 20)); // 128 MiB

    prep_kernel<<<192, 256, 0, stream>>>(We, dec, Wd, bd, be, WeTcB, dp);
    scores_gemm_kernel<<<(B_ * S_ / BM) * (H_ / BN), 256, 0, stream>>>(
        enc, WeTcB, Wo, dp, parts, encB);
    stats_kernel<<<B_, 256, 0, stream>>>(parts, stats);
    ctx_partial_bf16<<<B_ * 32, 256, 0, stream>>>(encB, parts, stats, part);
    ctx_reduce<<<B_ * E_ / 256, 256, 0, stream>>>(part, stats, out);
}

// Round 8
// 489.265 us; speedup vs baseline: 1.0509x; 1.0509x over previous
//
#include <hip/hip_runtime.h>
#include <hip/hip_bf16.h>
#include <math.h>

#define B_ 16
#define S_ 4096
#define E_ 1024
#define H_ 512

#define BM 128
#define BN 128
#define BK 64
#define NCHUNK (E_ / BK)  // 16

typedef short bf16x8 __attribute__((ext_vector_type(8)));
typedef unsigned short u16x8 __attribute__((ext_vector_type(8)));
typedef float f32x4 __attribute__((ext_vector_type(4)));

__device__ inline unsigned short f2bf(float x) {
    __hip_bfloat16 h = __float2bfloat16(x);
    return *(unsigned short*)&h;
}
__device__ inline float bf2f(unsigned short u) {
    unsigned int x = ((unsigned int)u) << 16;
    float f;
    __builtin_memcpy(&f, &x, 4);
    return f;
}
__device__ __forceinline__ void gld16(const void* g, void* l) {
    __builtin_amdgcn_global_load_lds(
        (const __attribute__((address_space(1))) void*)g,
        (__attribute__((address_space(3))) void*)l, 16, 0, 0);
}

// Prep:
//  blocks 0..63   : We -> WeTcB bf16, swizzled-chunk layout:
//                   WeTcB[c*32768 + n*64 + cp*8 + j] = We[k][n],
//                   k = c*64 + (cp ^ (n&7))*8 + j   (bank-conflict-free frags)
//  blocks 64..191 : dp[b][h] = dec[b,:].Wd[:,h] + bd[h] + be[h] (bo: softmax-inv)
__global__ __launch_bounds__(256) void prep_kernel(
    const float* __restrict__ We, const float* __restrict__ dec,
    const float* __restrict__ Wd, const float* __restrict__ bd,
    const float* __restrict__ be, unsigned short* __restrict__ WeTcB,
    float* __restrict__ dp) {
    __shared__ float red[4][64];
    int bid = blockIdx.x, t = threadIdx.x;
    if (bid < 64) {
        int c = bid >> 2, n0t = (bid & 3) * 128;
#pragma unroll 4
        for (int it = 0; it < 32; ++it) {
            int o = it * 256 + t;
            int n_rel = o >> 6, within = o & 63;
            int cp = within >> 3, j = within & 7;
            int n = n0t + n_rel;
            int k = c * 64 + ((cp ^ (n & 7)) << 3) + j;
            WeTcB[c * 32768 + n * 64 + within] = f2bf(We[(size_t)k * H_ + n]);
        }
    } else {
        int id = bid - 64;
        int b = id >> 3, hc = id & 7;
        int h = hc * 64 + (t & 63);
        int ec = t >> 6;
        const float* dr = dec + b * E_ + ec * 256;
        const float* wp = Wd + (size_t)(ec * 256) * H_ + h;
        float acc = 0.f;
#pragma unroll 8
        for (int e = 0; e < 256; ++e) acc = fmaf(dr[e], wp[(size_t)e * H_], acc);
        red[ec][t & 63] = acc;
        __syncthreads();
        if (t < 64) {
            int hh = hc * 64 + t;
            dp[b * H_ + hh] = red[0][t] + red[1][t] + red[2][t] + red[3][t] + bd[hh] + be[hh];
        }
    }
}

// Fused GEMM: parts[nt][b][s] = sum_{h in nt's 128} tanh(enc@We + dp)*Wo
// 128x128x64 tiles, 4 waves (2m x 2n), acc 4x4 frags = 64 AGPR/lane.
// A: raw fp32 enc DMA'd to LDS via global_load_lds (async, swizzle via per-lane
//    gather addrs: phys 32B-granule = logical ^ (row&7)); converted to bf16 at
//    frag-read time (2x ds_read_b128 + cvt). No sync global access, no conv pass.
// B: pre-swizzled bf16 WeTcB staged via global_load_lds.
// Block remap: 4 nt-siblings of an m-tile on the same XCD (bid%8) -> fp32
// A-tile fetched once into that XCD's L2.
__global__ __launch_bounds__(256, 3) void scores_gemm_kernel(
    const float* __restrict__ enc, const unsigned short* __restrict__ WeTcB,
    const float* __restrict__ Wo, const float* __restrict__ dp,
    float* __restrict__ parts) {
    __shared__ float sAf[BM * BK];          // 32 KB fp32 A tile (swizzled)
    __shared__ unsigned short sB[BN * BK];  // 16 KB
    __shared__ float sRed[2][BM];           // 1 KB

    int tid = threadIdx.x;
    int w = tid >> 6, l = tid & 63;
    int l16 = l & 15, quad = l >> 4;
    int wm = w & 1, wn = w >> 1;
    int bid = blockIdx.x;
    int xcd = bid & 7;
    int sq = bid >> 3;
    int nt = sq & 3;                             // sibling index (same XCD for all 4)
    size_t mt = (size_t)((sq >> 2) << 3) + xcd;  // [0,512)
    size_t m0 = mt * BM;
    int n0 = nt * BN;
    int b = (int)(m0 >> 12);

    // ---- A staging lane constants (fp32 DMA, swizzled gather) ----
    // wave w, issue i covers rows w*32 + i*4 + (l>>4); lane slot phys16 = l&15.
    // logical g32 = ((l&15)>>1) ^ (r&7); elem off = g32*8 + (l&1)*4.
    // r&7 = ((i&1)*4 + (l>>4)) & 7  -> two patterns by issue parity.
    int arow_l = l >> 4;               // 0..3
    int p32 = (l & 15) >> 1;           // phys 32B granule 0..7
    int half_l = l & 1;
    int ge = (p32 ^ arow_l) * 8 + half_l * 4;              // i even
    int go = (p32 ^ ((arow_l + 4) & 7)) * 8 + half_l * 4;  // i odd
    const float* gA_even = enc + (m0 + w * 32 + arow_l) * E_ + ge;
    const float* gA_odd  = enc + (m0 + w * 32 + arow_l) * E_ + go;
    float* sAf_w = sAf + (w * 32) * BK;  // + i*4*BK per issue (row*64 floats)
    // ---- B staging lane constants ----
    const unsigned short* gB = WeTcB + (size_t)n0 * BK + (w * 8) * BK + l * 8;
    unsigned short* sBb = sB + (w * 8) * BK;

    f32x4 acc[4][4];
#pragma unroll
    for (int i = 0; i < 4; ++i)
#pragma unroll
        for (int j = 0; j < 4; ++j) acc[i][j] = (f32x4)0.f;

    int brow = (wn * 64 + l16) * BK;
    int sw = l16 & 7;
    int arowf = (wm * 64 + l16) * BK;  // float units (row*64)

    for (int c = 0; c < NCHUNK; ++c) {
        __syncthreads();  // prior chunk's frag reads complete
        int k0 = c * BK;
        // B: 4 issues/wave (16 KB total)
#pragma unroll
        for (int i = 0; i < 4; ++i)
            gld16(gB + (size_t)c * (H_ * BK) + i * 32 * BK, sBb + i * 32 * BK);
        // A: 8 issues/wave (32 KB fp32 total), swizzle in gather addresses
#pragma unroll
        for (int i = 0; i < 8; ++i) {
            const float* src = ((i & 1) ? gA_odd : gA_even) + (size_t)i * 4 * E_ + k0;
            gld16(src, sAf_w + i * 4 * BK);
        }
        __syncthreads();  // DMA landed (compiler drains vmcnt before barrier)
#pragma unroll
        for (int half = 0; half < 2; ++half) {
            int kq = half * 4 + quad;
            bf16x8 aR[4], bR[4];
#pragma unroll
            for (int i = 0; i < 4; ++i) {
                int phys = (kq ^ sw) * 8;
                const float* ap = sAf + arowf + i * 16 * BK + phys;
                f32x4 lo = *(const f32x4*)(ap);
                f32x4 hi = *(const f32x4*)(ap + 4);
                u16x8 u;
                u[0] = f2bf(lo[0]); u[1] = f2bf(lo[1]); u[2] = f2bf(lo[2]); u[3] = f2bf(lo[3]);
                u[4] = f2bf(hi[0]); u[5] = f2bf(hi[1]); u[6] = f2bf(hi[2]); u[7] = f2bf(hi[3]);
                aR[i] = *(bf16x8*)&u;
            }
#pragma unroll
            for (int j = 0; j < 4; ++j)
                bR[j] = *(const bf16x8*)(sB + brow + j * 16 * BK + ((kq ^ sw) << 3));
#pragma unroll
            for (int i = 0; i < 4; ++i)
#pragma unroll
                for (int j = 0; j < 4; ++j)
                    acc[i][j] = __builtin_amdgcn_mfma_f32_16x16x32_bf16(aR[i], bR[j], acc[i][j], 0, 0, 0);
        }
    }

    // Epilogue: tanh(acc + dp) * Wo, partial reduce over this block's 128 h.
    float dpv[4], wov[4];
    const float* dpb = dp + b * H_;
#pragma unroll
    for (int j = 0; j < 4; ++j) {
        int h = n0 + wn * 64 + j * 16 + l16;
        dpv[j] = dpb[h];
        wov[j] = Wo[h];
    }
#pragma unroll
    for (int i = 0; i < 4; ++i)
#pragma unroll
        for (int r = 0; r < 4; ++r) {
            float s = 0.f;
#pragma unroll
            for (int j = 0; j < 4; ++j) {
                float x = acc[i][j][r] + dpv[j];
                float e = __expf(2.f * x);
                s += (1.f - 2.f / (e + 1.f)) * wov[j];
            }
            s += __shfl_xor(s, 1, 64);
            s += __shfl_xor(s, 2, 64);
            s += __shfl_xor(s, 4, 64);
            s += __shfl_xor(s, 8, 64);
            if (l16 == 0) sRed[wn][wm * 64 + i * 16 + quad * 4 + r] = s;
        }
    __syncthreads();
    if (tid < BM) {
        int s_in = (int)(m0 & (S_ - 1)) + tid;
        parts[(size_t)(nt * B_ + b) * S_ + s_in] = sRed[0][tid] + sRed[1][tid];
    }
}

// Flash-style ctx partials from fp32 enc: per (b, 128-s chunk), local max m_c,
// unnormalized weights exp(sc - m_c), Z_c = sum. Thread: 8 e-cols, 64 s-rows.
// 64 partial slabs per b + per-chunk (m_c, Z_c).
__global__ __launch_bounds__(256) void ctx_partial_f32(
    const float* __restrict__ enc, const float* __restrict__ parts,
    float* __restrict__ part, float2* __restrict__ statsC) {
    int b = blockIdx.x >> 5;
    int c = blockIdx.x & 31;
    int s0 = c * 128;
    int tid = threadIdx.x;
    __shared__ float w[128];
    __shared__ float redm[2], redz[2];
    float sc = -1e30f;
    if (tid < 128) {
        size_t idx = (size_t)b * S_ + s0 + tid;
        sc = parts[(size_t)(0 * B_) * S_ + idx] + parts[(size_t)(1 * B_) * S_ + idx] +
             parts[(size_t)(2 * B_) * S_ + idx] + parts[(size_t)(3 * B_) * S_ + idx];
        w[tid] = sc;
    }
    __syncthreads();
    // local max over 128 scores (threads 0..127 hold one each; 2 waves)
    float m = sc;
    for (int off = 32; off; off >>= 1) m = fmaxf(m, __shfl_xor(m, off, 64));
    if (tid < 128 && (tid & 63) == 0) redm[tid >> 6] = m;
    __syncthreads();
    float mc = fmaxf(redm[0], redm[1]);
    float z = 0.f;
    if (tid < 128) {
        float e = __expf(w[tid] - mc);
        z = e;
        w[tid] = e;  // safe: every thread reads w only after next barrier
    }
    for (int off = 32; off; off >>= 1) z += __shfl_xor(z, off, 64);
    if (tid < 128 && (tid & 63) == 0) redz[tid >> 6] = z;
    __syncthreads();
    if (tid == 0) statsC[b * 32 + c] = make_float2(mc, redz[0] + redz[1]);

    int e8 = (tid & 127) * 8;
    int sh = tid >> 7;
    const float* base = enc + ((size_t)b * S_ + s0 + sh * 64) * E_ + e8;
    const float* wp = w + sh * 64;
    float acc[8];
#pragma unroll
    for (int t = 0; t < 8; ++t) acc[t] = 0.f;
    for (int s = 0; s < 64; s += 4) {
        float4 v0a = *(const float4*)(base + (size_t)(s + 0) * E_);
        float4 v0b = *(const float4*)(base + (size_t)(s + 0) * E_ + 4);
        float4 v1a = *(const float4*)(base + (size_t)(s + 1) * E_);
        float4 v1b = *(const float4*)(base + (size_t)(s + 1) * E_ + 4);
        float4 v2a = *(const float4*)(base + (size_t)(s + 2) * E_);
        float4 v2b = *(const float4*)(base + (size_t)(s + 2) * E_ + 4);
        float4 v3a = *(const float4*)(base + (size_t)(s + 3) * E_);
        float4 v3b = *(const float4*)(base + (size_t)(s + 3) * E_ + 4);
        float w0 = wp[s], w1 = wp[s + 1], w2 = wp[s + 2], w3 = wp[s + 3];
        acc[0] = fmaf(w0, v0a.x, acc[0]); acc[1] = fmaf(w0, v0a.y, acc[1]);
        acc[2] = fmaf(w0, v0a.z, acc[2]); acc[3] = fmaf(w0, v0a.w, acc[3]);
        acc[4] = fmaf(w0, v0b.x, acc[4]); acc[5] = fmaf(w0, v0b.y, acc[5]);
        acc[6] = fmaf(w0, v0b.z, acc[6]); acc[7] = fmaf(w0, v0b.w, acc[7]);
        acc[0] = fmaf(w1, v1a.x, acc[0]); acc[1] = fmaf(w1, v1a.y, acc[1]);
        acc[2] = fmaf(w1, v1a.z, acc[2]); acc[3] = fmaf(w1, v1a.w, acc[3]);
        acc[4] = fmaf(w1, v1b.x, acc[4]); acc[5] = fmaf(w1, v1b.y, acc[5]);
        acc[6] = fmaf(w1, v1b.z, acc[6]); acc[7] = fmaf(w1, v1b.w, acc[7]);
        acc[0] = fmaf(w2, v2a.x, acc[0]); acc[1] = fmaf(w2, v2a.y, acc[1]);
        acc[2] = fmaf(w2, v2a.z, acc[2]); acc[3] = fmaf(w2, v2a.w, acc[3]);
        acc[4] = fmaf(w2, v2b.x, acc[4]); acc[5] = fmaf(w2, v2b.y, acc[5]);
        acc[6] = fmaf(w2, v2b.z, acc[6]); acc[7] = fmaf(w2, v2b.w, acc[7]);
        acc[0] = fmaf(w3, v3a.x, acc[0]); acc[1] = fmaf(w3, v3a.y, acc[1]);
        acc[2] = fmaf(w3, v3a.z, acc[2]); acc[3] = fmaf(w3, v3a.w, acc[3]);
        acc[4] = fmaf(w3, v3b.x, acc[4]); acc[5] = fmaf(w3, v3b.y, acc[5]);
        acc[6] = fmaf(w3, v3b.z, acc[6]); acc[7] = fmaf(w3, v3b.w, acc[7]);
    }
    float* po = part + ((size_t)(b * 64 + c * 2 + sh)) * E_ + e8;
    *(float4*)(po) = make_float4(acc[0], acc[1], acc[2], acc[3]);
    *(float4*)(po + 4) = make_float4(acc[4], acc[5], acc[6], acc[7]);
}

// Combine: out[b][e] = sum_c part[b][slab][e]*exp(m_c - M) / sum_c Z_c*exp(m_c - M)
// block = (b, e-quarter); 64 blocks.
__global__ __launch_bounds__(256) void ctx_reduce(const float* __restrict__ part,
                                                  const float2* __restrict__ statsC,
                                                  float* __restrict__ out) {
    int b = blockIdx.x >> 2;
    int e = (blockIdx.x & 3) * 256 + threadIdx.x;
    __shared__ float ef[32];
    if (threadIdx.x == 0) {
        float M = -1e30f;
        float2 st[32];
#pragma unroll 8
        for (int c = 0; c < 32; ++c) {
            st[c] = statsC[b * 32 + c];
            M = fmaxf(M, st[c].x);
        }
        float Z = 0.f;
#pragma unroll 8
        for (int c = 0; c < 32; ++c) ef[c] = __expf(st[c].x - M);
#pragma unroll 8
        for (int c = 0; c < 32; ++c) Z += st[c].y * ef[c];
        float inv = 1.f / Z;
#pragma unroll 8
        for (int c = 0; c < 32; ++c) ef[c] *= inv;
    }
    __syncthreads();
    const float* p = part + (size_t)b * 64 * E_ + e;
    float s0 = 0.f, s1 = 0.f, s2 = 0.f, s3 = 0.f;
    for (int sl = 0; sl < 64; sl += 4) {
        s0 += p[(size_t)(sl + 0) * E_] * ef[(sl + 0) >> 1];
        s1 += p[(size_t)(sl + 1) * E_] * ef[(sl + 1) >> 1];
        s2 += p[(size_t)(sl + 2) * E_] * ef[(sl + 2) >> 1];
        s3 += p[(size_t)(sl + 3) * E_] * ef[(sl + 3) >> 1];
    }
    out[(size_t)b * E_ + e] = (s0 + s1) + (s2 + s3);
}

extern "C" void kernel_launch(void* const* d_in, const int* in_sizes, int n_in,
                              void* d_out, int out_size, void* d_ws, size_t ws_size,
                              hipStream_t stream) {
    const float* enc = (const float*)d_in[0];  // [16,4096,1024]
    const float* dec = (const float*)d_in[1];  // [16,1024]
    const float* We  = (const float*)d_in[2];  // [1024,512]
    const float* be  = (const float*)d_in[3];  // [512]
    const float* Wd  = (const float*)d_in[4];  // [1024,512]
    const float* bd  = (const float*)d_in[5];  // [512]
    const float* Wo  = (const float*)d_in[6];  // [512,1]
    float* out = (float*)d_out;                // [16,1024]

    char* wsp = (char*)d_ws;
    unsigned short* WeTcB = (unsigned short*)wsp;              // 1 MiB
    float* dp = (float*)(wsp + (1 << 20));                     // 32 KiB
    float2* statsC = (float2*)(wsp + (1 << 20) + (32 << 10));  // 4 KiB
    float* parts = (float*)(wsp + (1 << 20) + (64 << 10));     // 1 MiB (4 slabs)
    float* part = (float*)(wsp + (4 << 20));                   // 4 MiB

    prep_kernel<<<192, 256, 0, stream>>>(We, dec, Wd, bd, be, WeTcB, dp);
    scores_gemm_kernel<<<(B_ * S_ / BM) * (H_ / BN), 256, 0, stream>>>(
        enc, WeTcB, Wo, dp, parts);
    ctx_partial_f32<<<B_ * 32, 256, 0, stream>>>(enc, parts, part, statsC);
    ctx_reduce<<<B_ * 4, 256, 0, stream>>>(part, statsC, out);
}

// Round 9
// 487.313 us; speedup vs baseline: 1.0551x; 1.0040x over previous
//
#include <hip/hip_runtime.h>
#include <hip/hip_bf16.h>
#include <math.h>

#define B_ 16
#define S_ 4096
#define E_ 1024
#define H_ 512

#define BM 128
#define BN 128
#define BK 64
#define NCHUNK (E_ / BK)  // 16

typedef short bf16x8 __attribute__((ext_vector_type(8)));
typedef unsigned short u16x8 __attribute__((ext_vector_type(8)));
typedef float f32x4 __attribute__((ext_vector_type(4)));

__device__ inline unsigned short f2bf(float x) {
    __hip_bfloat16 h = __float2bfloat16(x);
    return *(unsigned short*)&h;
}
__device__ __forceinline__ void gld16(const void* g, void* l) {
    __builtin_amdgcn_global_load_lds(
        (const __attribute__((address_space(1))) void*)g,
        (__attribute__((address_space(3))) void*)l, 16, 0, 0);
}

// Prep:
//  blocks 0..63   : We -> WeTcB bf16, swizzled-chunk layout:
//                   WeTcB[c*32768 + n*64 + cp*8 + j] = We[k][n],
//                   k = c*64 + (cp ^ (n&7))*8 + j   (bank-conflict-free frags)
//  blocks 64..191 : dp[b][h] = dec[b,:].Wd[:,h] + bd[h] + be[h] (bo: softmax-inv)
__global__ __launch_bounds__(256) void prep_kernel(
    const float* __restrict__ We, const float* __restrict__ dec,
    const float* __restrict__ Wd, const float* __restrict__ bd,
    const float* __restrict__ be, unsigned short* __restrict__ WeTcB,
    float* __restrict__ dp) {
    __shared__ float red[4][64];
    int bid = blockIdx.x, t = threadIdx.x;
    if (bid < 64) {
        int c = bid >> 2, n0t = (bid & 3) * 128;
#pragma unroll 4
        for (int it = 0; it < 32; ++it) {
            int o = it * 256 + t;
            int n_rel = o >> 6, within = o & 63;
            int cp = within >> 3, j = within & 7;
            int n = n0t + n_rel;
            int k = c * 64 + ((cp ^ (n & 7)) << 3) + j;
            WeTcB[c * 32768 + n * 64 + within] = f2bf(We[(size_t)k * H_ + n]);
        }
    } else {
        int id = bid - 64;
        int b = id >> 3, hc = id & 7;
        int h = hc * 64 + (t & 63);
        int ec = t >> 6;
        const float* dr = dec + b * E_ + ec * 256;
        const float* wp = Wd + (size_t)(ec * 256) * H_ + h;
        float acc = 0.f;
#pragma unroll 8
        for (int e = 0; e < 256; ++e) acc = fmaf(dr[e], wp[(size_t)e * H_], acc);
        red[ec][t & 63] = acc;
        __syncthreads();
        if (t < 64) {
            int hh = hc * 64 + t;
            dp[b * H_ + hh] = red[0][t] + red[1][t] + red[2][t] + red[3][t] + bd[hh] + be[hh];
        }
    }
}

// Fused GEMM: parts[nt][b][s] = sum_{h in nt's 128} tanh(enc@We + dp)*Wo
// A: raw fp32 enc DMA'd to LDS (global_load_lds, async). Conflict-free 16B-
//    granule swizzle: slot s of row r holds logical granule16 (s ^ (r&15)),
//    realized via per-lane DMA source addrs (4 patterns by issue i&3).
//    Frag read = 2x ds_read_b128 at slots (2kq)^l16 and (2kq+1)^l16 -> every
//    4-bank group gets exactly 2 lanes (free), then cvt to bf16.
// B: pre-swizzled bf16 WeTcB staged via global_load_lds (0-conflict, r7-proven).
// Block remap: 4 nt-siblings of an m-tile on the same XCD (bid%8) -> fp32
// A-tile fetched once into that XCD's L2.
__global__ __launch_bounds__(256, 3) void scores_gemm_kernel(
    const float* __restrict__ enc, const unsigned short* __restrict__ WeTcB,
    const float* __restrict__ Wo, const float* __restrict__ dp,
    float* __restrict__ parts) {
    __shared__ float sAf[BM * BK];          // 32 KB fp32 A tile (swizzled)
    __shared__ unsigned short sB[BN * BK];  // 16 KB
    __shared__ float sRed[2][BM];           // 1 KB

    int tid = threadIdx.x;
    int w = tid >> 6, l = tid & 63;
    int l16 = l & 15, quad = l >> 4;
    int wm = w & 1, wn = w >> 1;
    int bid = blockIdx.x;
    int xcd = bid & 7;
    int sq = bid >> 3;
    int nt = sq & 3;                             // sibling index (same XCD for all 4)
    size_t mt = (size_t)((sq >> 2) << 3) + xcd;  // [0,512)
    size_t m0 = mt * BM;
    int n0 = nt * BN;
    int b = (int)(m0 >> 12);

    // ---- A staging lane constants (fp32 DMA, 16B-granule swizzled gather) ----
    // issue i covers rows w*32 + i*4 + (l>>4); lane dest slot = l&15.
    // source logical granule16 g = (l&15) ^ ((i*4 + (l>>4)) & 15); i*4&15 has
    // period 4 in i -> 4 precomputed pointers.
    int rl = l >> 4;   // row-in-issue 0..3
    int sl = l & 15;   // dest slot
    const float* gA4[4];
#pragma unroll
    for (int p = 0; p < 4; ++p) {
        int g = sl ^ ((p * 4 + rl) & 15);
        gA4[p] = enc + (m0 + w * 32 + rl) * E_ + g * 4;
    }
    float* sAf_w = sAf + (w * 32) * BK;
    // ---- B staging lane constants ----
    const unsigned short* gB = WeTcB + (size_t)n0 * BK + (w * 8) * BK + l * 8;
    unsigned short* sBb = sB + (w * 8) * BK;

    f32x4 acc[4][4];
#pragma unroll
    for (int i = 0; i < 4; ++i)
#pragma unroll
        for (int j = 0; j < 4; ++j) acc[i][j] = (f32x4)0.f;

    int brow = (wn * 64 + l16) * BK;
    int sw = l16 & 7;
    int arowf = (wm * 64 + l16) * BK;  // float units

    for (int c = 0; c < NCHUNK; ++c) {
        __syncthreads();  // prior chunk's frag reads complete
        int k0 = c * BK;
        // B: 4 issues/wave (16 KB total)
#pragma unroll
        for (int i = 0; i < 4; ++i)
            gld16(gB + (size_t)c * (H_ * BK) + i * 32 * BK, sBb + i * 32 * BK);
        // A: 8 issues/wave (32 KB fp32 total), swizzle in gather addresses
#pragma unroll
        for (int i = 0; i < 8; ++i)
            gld16(gA4[i & 3] + (size_t)i * 4 * E_ + k0, sAf_w + i * 4 * BK);
        __syncthreads();  // DMA landed (compiler drains vmcnt before barrier)
#pragma unroll
        for (int half = 0; half < 2; ++half) {
            int kq = half * 4 + quad;
            bf16x8 aR[4], bR[4];
            int s_lo = (2 * kq) ^ l16;
            int s_hi = s_lo ^ 1;
#pragma unroll
            for (int i = 0; i < 4; ++i) {
                const float* ap = sAf + arowf + i * 16 * BK;
                f32x4 lo = *(const f32x4*)(ap + s_lo * 4);
                f32x4 hi = *(const f32x4*)(ap + s_hi * 4);
                u16x8 u;
                u[0] = f2bf(lo[0]); u[1] = f2bf(lo[1]); u[2] = f2bf(lo[2]); u[3] = f2bf(lo[3]);
                u[4] = f2bf(hi[0]); u[5] = f2bf(hi[1]); u[6] = f2bf(hi[2]); u[7] = f2bf(hi[3]);
                aR[i] = *(bf16x8*)&u;
            }
#pragma unroll
            for (int j = 0; j < 4; ++j)
                bR[j] = *(const bf16x8*)(sB + brow + j * 16 * BK + ((kq ^ sw) << 3));
#pragma unroll
            for (int i = 0; i < 4; ++i)
#pragma unroll
                for (int j = 0; j < 4; ++j)
                    acc[i][j] = __builtin_amdgcn_mfma_f32_16x16x32_bf16(aR[i], bR[j], acc[i][j], 0, 0, 0);
        }
    }

    // Epilogue: tanh(acc + dp) * Wo, partial reduce over this block's 128 h.
    float dpv[4], wov[4];
    const float* dpb = dp + b * H_;
#pragma unroll
    for (int j = 0; j < 4; ++j) {
        int h = n0 + wn * 64 + j * 16 + l16;
        dpv[j] = dpb[h];
        wov[j] = Wo[h];
    }
#pragma unroll
    for (int i = 0; i < 4; ++i)
#pragma unroll
        for (int r = 0; r < 4; ++r) {
            float s = 0.f;
#pragma unroll
            for (int j = 0; j < 4; ++j) {
                float x = acc[i][j][r] + dpv[j];
                float e = __expf(2.f * x);
                s += (1.f - 2.f / (e + 1.f)) * wov[j];
            }
            s += __shfl_xor(s, 1, 64);
            s += __shfl_xor(s, 2, 64);
            s += __shfl_xor(s, 4, 64);
            s += __shfl_xor(s, 8, 64);
            if (l16 == 0) sRed[wn][wm * 64 + i * 16 + quad * 4 + r] = s;
        }
    __syncthreads();
    if (tid < BM) {
        int s_in = (int)(m0 & (S_ - 1)) + tid;
        parts[(size_t)(nt * B_ + b) * S_ + s_in] = sRed[0][tid] + sRed[1][tid];
    }
}

// Flash-style ctx partials from fp32 enc: per (b, 128-s chunk), local max m_c,
// unnormalized weights exp(sc - m_c), Z_c = sum. Thread: 8 e-cols, 64 s-rows.
__global__ __launch_bounds__(256) void ctx_partial_f32(
    const float* __restrict__ enc, const float* __restrict__ parts,
    float* __restrict__ part, float2* __restrict__ statsC) {
    int b = blockIdx.x >> 5;
    int c = blockIdx.x & 31;
    int s0 = c * 128;
    int tid = threadIdx.x;
    __shared__ float w[128];
    __shared__ float redm[2], redz[2];
    float sc = -1e30f;
    if (tid < 128) {
        size_t idx = (size_t)b * S_ + s0 + tid;
        sc = parts[(size_t)(0 * B_) * S_ + idx] + parts[(size_t)(1 * B_) * S_ + idx] +
             parts[(size_t)(2 * B_) * S_ + idx] + parts[(size_t)(3 * B_) * S_ + idx];
        w[tid] = sc;
    }
    __syncthreads();
    float m = sc;
    for (int off = 32; off; off >>= 1) m = fmaxf(m, __shfl_xor(m, off, 64));
    if (tid < 128 && (tid & 63) == 0) redm[tid >> 6] = m;
    __syncthreads();
    float mc = fmaxf(redm[0], redm[1]);
    float z = 0.f;
    if (tid < 128) {
        float e = __expf(w[tid] - mc);
        z = e;
        w[tid] = e;
    }
    for (int off = 32; off; off >>= 1) z += __shfl_xor(z, off, 64);
    if (tid < 128 && (tid & 63) == 0) redz[tid >> 6] = z;
    __syncthreads();
    if (tid == 0) statsC[b * 32 + c] = make_float2(mc, redz[0] + redz[1]);

    int e8 = (tid & 127) * 8;
    int sh = tid >> 7;
    const float* base = enc + ((size_t)b * S_ + s0 + sh * 64) * E_ + e8;
    const float* wp = w + sh * 64;
    float acc[8];
#pragma unroll
    for (int t = 0; t < 8; ++t) acc[t] = 0.f;
    for (int s = 0; s < 64; s += 4) {
        float4 v0a = *(const float4*)(base + (size_t)(s + 0) * E_);
        float4 v0b = *(const float4*)(base + (size_t)(s + 0) * E_ + 4);
        float4 v1a = *(const float4*)(base + (size_t)(s + 1) * E_);
        float4 v1b = *(const float4*)(base + (size_t)(s + 1) * E_ + 4);
        float4 v2a = *(const float4*)(base + (size_t)(s + 2) * E_);
        float4 v2b = *(const float4*)(base + (size_t)(s + 2) * E_ + 4);
        float4 v3a = *(const float4*)(base + (size_t)(s + 3) * E_);
        float4 v3b = *(const float4*)(base + (size_t)(s + 3) * E_ + 4);
        float w0 = wp[s], w1 = wp[s + 1], w2 = wp[s + 2], w3 = wp[s + 3];
        acc[0] = fmaf(w0, v0a.x, acc[0]); acc[1] = fmaf(w0, v0a.y, acc[1]);
        acc[2] = fmaf(w0, v0a.z, acc[2]); acc[3] = fmaf(w0, v0a.w, acc[3]);
        acc[4] = fmaf(w0, v0b.x, acc[4]); acc[5] = fmaf(w0, v0b.y, acc[5]);
        acc[6] = fmaf(w0, v0b.z, acc[6]); acc[7] = fmaf(w0, v0b.w, acc[7]);
        acc[0] = fmaf(w1, v1a.x, acc[0]); acc[1] = fmaf(w1, v1a.y, acc[1]);
        acc[2] = fmaf(w1, v1a.z, acc[2]); acc[3] = fmaf(w1, v1a.w, acc[3]);
        acc[4] = fmaf(w1, v1b.x, acc[4]); acc[5] = fmaf(w1, v1b.y, acc[5]);
        acc[6] = fmaf(w1, v1b.z, acc[6]); acc[7] = fmaf(w1, v1b.w, acc[7]);
        acc[0] = fmaf(w2, v2a.x, acc[0]); acc[1] = fmaf(w2, v2a.y, acc[1]);
        acc[2] = fmaf(w2, v2a.z, acc[2]); acc[3] = fmaf(w2, v2a.w, acc[3]);
        acc[4] = fmaf(w2, v2b.x, acc[4]); acc[5] = fmaf(w2, v2b.y, acc[5]);
        acc[6] = fmaf(w2, v2b.z, acc[6]); acc[7] = fmaf(w2, v2b.w, acc[7]);
        acc[0] = fmaf(w3, v3a.x, acc[0]); acc[1] = fmaf(w3, v3a.y, acc[1]);
        acc[2] = fmaf(w3, v3a.z, acc[2]); acc[3] = fmaf(w3, v3a.w, acc[3]);
        acc[4] = fmaf(w3, v3b.x, acc[4]); acc[5] = fmaf(w3, v3b.y, acc[5]);
        acc[6] = fmaf(w3, v3b.z, acc[6]); acc[7] = fmaf(w3, v3b.w, acc[7]);
    }
    float* po = part + ((size_t)(b * 64 + c * 2 + sh)) * E_ + e8;
    *(float4*)(po) = make_float4(acc[0], acc[1], acc[2], acc[3]);
    *(float4*)(po + 4) = make_float4(acc[4], acc[5], acc[6], acc[7]);
}

// Combine: out[b][e] = sum_c part*exp(m_c - M) / sum_c Z_c*exp(m_c - M)
__global__ __launch_bounds__(256) void ctx_reduce(const float* __restrict__ part,
                                                  const float2* __restrict__ statsC,
                                                  float* __restrict__ out) {
    int b = blockIdx.x >> 2;
    int e = (blockIdx.x & 3) * 256 + threadIdx.x;
    __shared__ float ef[32];
    if (threadIdx.x == 0) {
        float M = -1e30f;
        float2 st[32];
#pragma unroll 8
        for (int c = 0; c < 32; ++c) {
            st[c] = statsC[b * 32 + c];
            M = fmaxf(M, st[c].x);
        }
        float Z = 0.f;
#pragma unroll 8
        for (int c = 0; c < 32; ++c) ef[c] = __expf(st[c].x - M);
#pragma unroll 8
        for (int c = 0; c < 32; ++c) Z += st[c].y * ef[c];
        float inv = 1.f / Z;
#pragma unroll 8
        for (int c = 0; c < 32; ++c) ef[c] *= inv;
    }
    __syncthreads();
    const float* p = part + (size_t)b * 64 * E_ + e;
    float s0 = 0.f, s1 = 0.f, s2 = 0.f, s3 = 0.f;
    for (int sl = 0; sl < 64; sl += 4) {
        s0 += p[(size_t)(sl + 0) * E_] * ef[(sl + 0) >> 1];
        s1 += p[(size_t)(sl + 1) * E_] * ef[(sl + 1) >> 1];
        s2 += p[(size_t)(sl + 2) * E_] * ef[(sl + 2) >> 1];
        s3 += p[(size_t)(sl + 3) * E_] * ef[(sl + 3) >> 1];
    }
    out[(size_t)b * E_ + e] = (s0 + s1) + (s2 + s3);
}

extern "C" void kernel_launch(void* const* d_in, const int* in_sizes, int n_in,
                              void* d_out, int out_size, void* d_ws, size_t ws_size,
                              hipStream_t stream) {
    const float* enc = (const float*)d_in[0];  // [16,4096,1024]
    const float* dec = (const float*)d_in[1];  // [16,1024]
    const float* We  = (const float*)d_in[2];  // [1024,512]
    const float* be  = (const float*)d_in[3];  // [512]
    const float* Wd  = (const float*)d_in[4];  // [1024,512]
    const float* bd  = (const float*)d_in[5];  // [512]
    const float* Wo  = (const float*)d_in[6];  // [512,1]
    float* out = (float*)d_out;                // [16,1024]

    char* wsp = (char*)d_ws;
    unsigned short* WeTcB = (unsigned short*)wsp;              // 1 MiB
    float* dp = (float*)(wsp + (1 << 20));                     // 32 KiB
    float2* statsC = (float2*)(wsp + (1 << 20) + (32 << 10));  // 4 KiB
    float* parts = (float*)(wsp + (1 << 20) + (64 << 10));     // 1 MiB (4 slabs)
    float* part = (float*)(wsp + (4 << 20));                   // 4 MiB

    prep_kernel<<<192, 256, 0, stream>>>(We, dec, Wd, bd, be, WeTcB, dp);
    scores_gemm_kernel<<<(B_ * S_ / BM) * (H_ / BN), 256, 0, stream>>>(
        enc, WeTcB, Wo, dp, parts);
    ctx_partial_f32<<<B_ * 32, 256, 0, stream>>>(enc, parts, part, statsC);
    ctx_reduce<<<B_ * 4, 256, 0, stream>>>(part, statsC, out);
}